// Round 1
// baseline (119.937 us; speedup 1.0000x reference)
//
#include <hip/hip_runtime.h>
#include <math.h>

// RoI "mod-7" max pooling, matching the JAX reference exactly.
// x: (N=2, C=512, h=50, w=50) fp32, rois: (R, 5) fp32 [b, y1, x1, y2, x2]*16
// out: (R, C, 7, 7) fp32.
//
// Layout choice: lanes run along the x (w) dimension so each row load is one
// coalesced <=200B transaction per wave. Bin-column maxes come from a 3-step
// stride-7 shuffle tree (lanes j, j+7, ..., j+49 -> lane j). Bin-row index i
// is a compile-time unrolled loop (rows y = y1+i, y1+i+7, ...) so the 7
// accumulators stay in registers (no dynamic indexing -> no scratch).

#define CH    512
#define IH    50
#define IW    50
#define NEG_INF (-__builtin_inff())

__global__ __launch_bounds__(256) void roipool_kernel(
    const float* __restrict__ x, const float* __restrict__ rois,
    float* __restrict__ out) {
  const int r      = blockIdx.y;
  const int cgroup = blockIdx.x;        // 0..15
  const int wave   = threadIdx.x >> 6;  // 0..3
  const int lane   = threadIdx.x & 63;

  // Decode roi (wave-uniform; scalar-ized by compiler).
  const float* rr = rois + r * 5;
  const int b  = (int)rr[0];
  const int y1 = (int)rintf(rr[1] * 0.0625f);
  const int x1 = (int)rintf(rr[2] * 0.0625f);
  const int y2 = min((int)rintf(rr[3] * 0.0625f), IH - 1);
  const int x2 = min((int)rintf(rr[4] * 0.0625f), IW - 1);
  const int fth  = y2 - y1 + 1;
  const int ftw  = x2 - x1 + 1;
  const int remh = fth % 7;
  const int remw = ftw % 7;

  const int c0 = cgroup * 32 + wave * 8;

  for (int cc = 0; cc < 8; ++cc) {
    const int c = c0 + cc;
    const float* base = x + ((size_t)(b * CH + c) * IH + y1) * IW + x1;

    float acc[7];
#pragma unroll
    for (int i = 0; i < 7; ++i) {
      float a = NEG_INF;
      // rows y = y1+i, y1+i+7, ... <= y2   (dy relative to y1)
      for (int dy = i; dy < fth; dy += 7) {
        const float* row = base + dy * IW;
        float v = (lane < ftw) ? row[lane] : NEG_INF;
        // segmented max over lanes {l, l+7, l+14, ..., l+49}
        v = fmaxf(v, __shfl_down(v, 7, 64));
        v = fmaxf(v, __shfl_down(v, 14, 64));
        v = fmaxf(v, __shfl_down(v, 28, 64));
        a = fmaxf(a, v);
      }
      acc[i] = a;  // lane j (<7) now holds bin (i, j) max
    }

    // Epilogue: pad-clamp (empty/partial bins -> max(val, 0)) + store.
    if (lane < 7) {
      const int j = lane;
      const bool padc = (remw != 0) && (j >= remw);
      float* o = out + (size_t)(r * CH + c) * 49 + j;
#pragma unroll
      for (int i = 0; i < 7; ++i) {
        float v = acc[i];
        const bool padr = (remh != 0) && (i >= remh);
        if (padr || padc) v = fmaxf(v, 0.0f);
        o[i * 7] = v;
      }
    }
  }
}

extern "C" void kernel_launch(void* const* d_in, const int* in_sizes, int n_in,
                              void* d_out, int out_size, void* d_ws, size_t ws_size,
                              hipStream_t stream) {
  const float* x    = (const float*)d_in[0];
  const float* rois = (const float*)d_in[1];
  float* out        = (float*)d_out;
  const int R = in_sizes[1] / 5;  // 128

  dim3 grid(16, R);   // 16 channel-groups x R rois = 2048 blocks
  dim3 block(256);    // 4 waves; each wave handles 8 channels
  roipool_kernel<<<grid, block, 0, stream>>>(x, rois, out);
}

// Round 2
// 78.049 us; speedup vs baseline: 1.5367x; 1.5367x over previous
//
#include <hip/hip_runtime.h>
#include <math.h>

// RoI "mod-7" max pooling (JAX reference-exact).
// x: (2, 512, 50, 50) fp32; rois: (R,5) fp32 [b, y1, x1, y2, x2]*16; out: (R, 512, 7, 7).
//
// Key facts exploited:
//  - roi window is at most 26x26 (sz <= 400, scale 1/16), so the window width
//    fits in 32 lanes -> each wave packs TWO channels: lane = half*32 + dx.
//  - bin-column reduction needs only dx in {j, j+7, j+14, j+21} (j+28 >= 26 is
//    always outside the window) -> TWO shuffles per bin-row, hoisted out of the
//    row loop (inner loop is load+fmax only -> pipelines freely).
//  - bin-row i is a compile-time unrolled loop (rows dy = i, i+7, ...) so the 7
//    accumulators are static registers and ~28 loads can be in flight.

#define CH 512
#define IH 50
#define IW 50
#define NEG_INF (-__builtin_inff())

__global__ __launch_bounds__(256) void roipool_kernel(
    const float* __restrict__ x, const float* __restrict__ rois,
    float* __restrict__ out) {
  const int r    = blockIdx.y;
  const int wave = threadIdx.x >> 6;   // 0..3 -> channel pair within block
  const int lane = threadIdx.x & 63;
  const int half = lane >> 5;          // which channel of the pair
  const int dx   = lane & 31;          // column within roi window (ftw <= 26)

  // roi decode (wave-uniform).
  const float* rr = rois + r * 5;
  const int b  = (int)rr[0];
  const int y1 = (int)rintf(rr[1] * 0.0625f);
  const int x1 = (int)rintf(rr[2] * 0.0625f);
  const int y2 = min((int)rintf(rr[3] * 0.0625f), IH - 1);
  const int x2 = min((int)rintf(rr[4] * 0.0625f), IW - 1);
  const int fth  = y2 - y1 + 1;
  const int ftw  = x2 - x1 + 1;
  const int remh = fth % 7;
  const int remw = ftw % 7;

  const int c = (blockIdx.x * 4 + wave) * 2 + half;  // this lane's channel
  const float* base = x + ((size_t)(b * CH + c) * IH + y1) * IW + x1;

  float acc[7];
#pragma unroll
  for (int i = 0; i < 7; ++i) {
    float a = NEG_INF;
    // rows dy = i, i+7, ... < fth  (at most 4 iterations since fth <= 26)
    for (int dy = i; dy < fth; dy += 7) {
      float v = NEG_INF;
      if (dx < ftw) v = base[dy * IW + dx];  // exec-masked load (OOB-safe)
      a = fmaxf(a, v);
    }
    // column reduce: lane j (<7 in each half) <- max over dx {j, j+7, j+14, j+21}
    a = fmaxf(a, __shfl_down(a, 7, 64));
    a = fmaxf(a, __shfl_down(a, 14, 64));
    acc[i] = a;
  }

  // Epilogue: pad-clamp (bins beyond remh/remw -> max(val, 0)) + store.
  if (dx < 7) {
    const int j = dx;
    const bool padc = (remw != 0) && (j >= remw);
    float* o = out + (size_t)(r * CH + c) * 49 + j;
#pragma unroll
    for (int i = 0; i < 7; ++i) {
      float v = acc[i];
      const bool padr = (remh != 0) && (i >= remh);
      if (padr | padc) v = fmaxf(v, 0.0f);
      o[i * 7] = v;
    }
  }
}

extern "C" void kernel_launch(void* const* d_in, const int* in_sizes, int n_in,
                              void* d_out, int out_size, void* d_ws, size_t ws_size,
                              hipStream_t stream) {
  const float* x    = (const float*)d_in[0];
  const float* rois = (const float*)d_in[1];
  float* out        = (float*)d_out;
  const int R = in_sizes[1] / 5;  // 128

  dim3 grid(64, R);   // 64 pair-groups x R rois = 8192 blocks
  dim3 block(256);    // 4 waves; each wave = 2 channels (half*32 + dx layout)
  roipool_kernel<<<grid, block, 0, stream>>>(x, rois, out);
}

// Round 3
// 73.328 us; speedup vs baseline: 1.6356x; 1.0644x over previous
//
#include <hip/hip_runtime.h>
#include <math.h>

// RoI "mod-7" max pooling (JAX reference-exact).
// x: (2, 512, 50, 50) fp32; rois: (R,5) fp32 [b, y1, x1, y2, x2]*16; out: (R, 512, 7, 7).
//
// Layout: roi window is at most 26x26 (sz <= 400, scale 1/16), so each wave
// packs TWO channels: lane = half*32 + dx (dx = column in window).
//
// R2 change: loop interchange for ILP. Outer loop = super-rows s (<=4,
// single dynamic trip count); inner 7 bin-rows fully unrolled -> 7
// independent loads in flight per super-row, acc dep chains <= 4 deep.
// (R1 had 7 separate dynamic loops -> one load per branch check, ILP ~2.)

#define CH 512
#define IH 50
#define IW 50
#define NEG_INF (-__builtin_inff())

__global__ __launch_bounds__(256) void roipool_kernel(
    const float* __restrict__ x, const float* __restrict__ rois,
    float* __restrict__ out) {
  const int r    = blockIdx.y;
  const int wave = threadIdx.x >> 6;   // 0..3 -> channel pair within block
  const int lane = threadIdx.x & 63;
  const int half = lane >> 5;          // which channel of the pair
  const int dx   = lane & 31;          // column within roi window (ftw <= 26)

  // roi decode (wave-uniform).
  const float* rr = rois + r * 5;
  const int b  = (int)rr[0];
  const int y1 = (int)rintf(rr[1] * 0.0625f);
  const int x1 = (int)rintf(rr[2] * 0.0625f);
  const int y2 = min((int)rintf(rr[3] * 0.0625f), IH - 1);
  const int x2 = min((int)rintf(rr[4] * 0.0625f), IW - 1);
  const int fth  = y2 - y1 + 1;
  const int ftw  = x2 - x1 + 1;
  const int remh = fth % 7;
  const int remw = ftw % 7;

  const int c = (blockIdx.x * 4 + wave) * 2 + half;  // this lane's channel
  const float* base = x + ((size_t)(b * CH + c) * IH + y1) * IW + x1 + dx;
  const bool colok = dx < ftw;

  float acc[7];
#pragma unroll
  for (int i = 0; i < 7; ++i) acc[i] = NEG_INF;

  const int nsr = (fth + 6) / 7;  // 1..4 super-rows
  for (int s = 0; s < nsr; ++s) {
    const float* rowb = base + (s * 7) * IW;
#pragma unroll
    for (int i = 0; i < 7; ++i) {
      const int dy = s * 7 + i;
      float v = NEG_INF;
      if ((dy < fth) & colok) v = rowb[i * IW];  // exec-masked, OOB-safe
      acc[i] = fmaxf(acc[i], v);
    }
  }

  // Column reduce + pad-clamp + store.
#pragma unroll
  for (int i = 0; i < 7; ++i) {
    float a = acc[i];
    // lane j (<7 in each half) <- max over dx {j, j+7, j+14, j+21}; dx+28 >= 26
    // is always outside the window, so two shuffle steps suffice.
    a = fmaxf(a, __shfl_down(a, 7, 64));
    a = fmaxf(a, __shfl_down(a, 14, 64));
    acc[i] = a;
  }

  if (dx < 7) {
    const int j = dx;
    const bool padc = (remw != 0) && (j >= remw);
    float* o = out + (size_t)(r * CH + c) * 49 + j;
#pragma unroll
    for (int i = 0; i < 7; ++i) {
      float v = acc[i];
      const bool padr = (remh != 0) && (i >= remh);
      if (padr | padc) v = fmaxf(v, 0.0f);
      o[i * 7] = v;
    }
  }
}

extern "C" void kernel_launch(void* const* d_in, const int* in_sizes, int n_in,
                              void* d_out, int out_size, void* d_ws, size_t ws_size,
                              hipStream_t stream) {
  const float* x    = (const float*)d_in[0];
  const float* rois = (const float*)d_in[1];
  float* out        = (float*)d_out;
  const int R = in_sizes[1] / 5;  // 128

  dim3 grid(64, R);   // 64 pair-groups x R rois = 8192 blocks
  dim3 block(256);    // 4 waves; each wave = 2 channels (half*32 + dx layout)
  roipool_kernel<<<grid, block, 0, stream>>>(x, rois, out);
}

// Round 4
// 71.047 us; speedup vs baseline: 1.6881x; 1.0321x over previous
//
#include <hip/hip_runtime.h>
#include <math.h>

// RoI "mod-7" max pooling (JAX reference-exact).
// x: (2, 512, 50, 50) fp32; rois: (R,5) fp32 [b, y1, x1, y2, x2]*16; out: (R, 512, 7, 7).
//
// Layout: roi window is at most 26x26 (sz <= 400, scale 1/16), so each wave
// packs channels 2-wide in lanes: lane = half*32 + dx, and additionally runs
// TWO channel chains (p=0,1) interleaved -> 4 channels/wave, 16k waves total.
//
// R3 changes (kill the per-load exec-mask dance):
//  - column OOB via CLAMPED address (cx = min(dx, ftw-1), always in-bounds,
//    computed once) + one v_cndmask to -inf per load. Loads issue unmasked.
//  - roi decode forced to SGPRs via readfirstlane -> row-validity is scalar
//    control flow: `full = fth/7` super-rows run with NO row checks; <=6 tail
//    rows use s_cbranch skips (row `fth` may lie past the allocation for the
//    last channel, so clamping rows is not an option -> branch).

#define CH 512
#define IH 50
#define IW 50
#define NEG_INF (-__builtin_inff())

__global__ __launch_bounds__(256) void roipool_kernel(
    const float* __restrict__ x, const float* __restrict__ rois,
    float* __restrict__ out) {
  const int r    = blockIdx.y;
  const int wave = threadIdx.x >> 6;   // 0..3
  const int lane = threadIdx.x & 63;
  const int half = lane >> 5;          // which channel of the lane-pair
  const int dx   = lane & 31;          // column within roi window (ftw <= 26)

  // roi decode, forced wave-uniform (SGPRs -> scalar branches, scalar addrs).
  const float* rr = rois + r * 5;
  const int b  = __builtin_amdgcn_readfirstlane((int)rr[0]);
  const int y1 = __builtin_amdgcn_readfirstlane((int)rintf(rr[1] * 0.0625f));
  const int x1 = __builtin_amdgcn_readfirstlane((int)rintf(rr[2] * 0.0625f));
  const int y2 = __builtin_amdgcn_readfirstlane(min((int)rintf(rr[3] * 0.0625f), IH - 1));
  const int x2 = __builtin_amdgcn_readfirstlane(min((int)rintf(rr[4] * 0.0625f), IW - 1));
  const int fth  = y2 - y1 + 1;
  const int ftw  = x2 - x1 + 1;
  const int remh = fth % 7;   // tail rows (also pad-row count trigger)
  const int remw = ftw % 7;
  const int full = fth / 7;   // 0..3 full super-rows

  // 4 channels per wave: lane-pair gives 2, p-loop chains give 2 more.
  const int cbase = (blockIdx.x * 4 + wave) * 4 + half * 2;  // ch cbase, cbase+1
  const int cx    = min(dx, ftw - 1);     // clamped column (always in-bounds)
  const bool colok = dx < ftw;

  const float* b0 = x + ((size_t)(b * CH + cbase) * IH + y1) * IW + x1 + cx;
  const float* b1 = b0 + (size_t)IH * IW;

  float acc0[7], acc1[7];
#pragma unroll
  for (int i = 0; i < 7; ++i) { acc0[i] = NEG_INF; acc1[i] = NEG_INF; }

  // Full super-rows: 14 unmasked loads per iteration, all independent.
  for (int s = 0; s < full; ++s) {
    const float* r0 = b0 + s * 7 * IW;
    const float* r1 = b1 + s * 7 * IW;
#pragma unroll
    for (int i = 0; i < 7; ++i) {
      float v0 = r0[i * IW];
      float v1 = r1[i * IW];
      v0 = colok ? v0 : NEG_INF;       // one cndmask per load
      v1 = colok ? v1 : NEG_INF;
      acc0[i] = fmaxf(acc0[i], v0);
      acc1[i] = fmaxf(acc1[i], v1);
    }
  }

  // Tail rows (0..6, wave-uniform count -> scalar skip branches).
  {
    const float* t0 = b0 + full * 7 * IW;
    const float* t1 = b1 + full * 7 * IW;
#pragma unroll
    for (int i = 0; i < 7; ++i) {
      if (i < remh) {
        float v0 = t0[i * IW];
        float v1 = t1[i * IW];
        v0 = colok ? v0 : NEG_INF;
        v1 = colok ? v1 : NEG_INF;
        acc0[i] = fmaxf(acc0[i], v0);
        acc1[i] = fmaxf(acc1[i], v1);
      }
    }
  }

  // Column reduce: lane j (<7 per half) <- max over dx {j, j+7, j+14, j+21}
  // (dx+28 >= 26 is always outside the window -> two shuffle steps).
#pragma unroll
  for (int i = 0; i < 7; ++i) {
    float a0 = acc0[i], a1 = acc1[i];
    a0 = fmaxf(a0, __shfl_down(a0, 7, 64));
    a1 = fmaxf(a1, __shfl_down(a1, 7, 64));
    a0 = fmaxf(a0, __shfl_down(a0, 14, 64));
    a1 = fmaxf(a1, __shfl_down(a1, 14, 64));
    acc0[i] = a0;
    acc1[i] = a1;
  }

  // Pad-clamp (bins beyond remh/remw -> max(val, 0)) + store.
  if (dx < 7) {
    const int j = dx;
    const bool padc = (remw != 0) && (j >= remw);
    float* o0 = out + (size_t)(r * CH + cbase) * 49 + j;
    float* o1 = o0 + 49;
#pragma unroll
    for (int i = 0; i < 7; ++i) {
      float v0 = acc0[i], v1 = acc1[i];
      const bool padr = (remh != 0) && (i >= remh);
      if (padr | padc) { v0 = fmaxf(v0, 0.0f); v1 = fmaxf(v1, 0.0f); }
      o0[i * 7] = v0;
      o1[i * 7] = v1;
    }
  }
}

extern "C" void kernel_launch(void* const* d_in, const int* in_sizes, int n_in,
                              void* d_out, int out_size, void* d_ws, size_t ws_size,
                              hipStream_t stream) {
  const float* x    = (const float*)d_in[0];
  const float* rois = (const float*)d_in[1];
  float* out        = (float*)d_out;
  const int R = in_sizes[1] / 5;  // 128

  dim3 grid(32, R);   // 32 channel-groups (16 ch/block) x R rois = 4096 blocks
  dim3 block(256);    // 4 waves; each wave = 4 channels (2 lane-packed x 2 chains)
  roipool_kernel<<<grid, block, 0, stream>>>(x, rois, out);
}